// Round 6
// baseline (611.676 us; speedup 1.0000x reference)
//
#include <hip/hip_runtime.h>
#include <math.h>

// x [64,4096,64] fp32, embedding [512,64] fp32
#define N_ROWS   262144
#define DIM      64
#define KCODES   512
#define NTHREADS 512                 // 8 waves
#define NBLOCKS  256                 // 1 block/CU (LDS-bound)
#define TILES    4                   // 32-row tiles per wave -> 1024 rows/block
#define ESTR     72                  // bf16 LDS stride (144 B) - conflict-free b128
#define BIAS     256.0f              // makes packed distances positive
#define T5       16384u              // flag threshold: 512 ulps << 5 bits

typedef float f32x4 __attribute__((ext_vector_type(4)));
typedef short s16x8 __attribute__((ext_vector_type(8)));
typedef short s16x4 __attribute__((ext_vector_type(4)));

// ws layout (bytes):
//   0       counts2d[256*512] int  (524288)
//   524288  lossPart[256]     f32  (1024)

__device__ __forceinline__ unsigned short f2bf(float f) {
    unsigned u = __float_as_uint(f);
    unsigned r = u + 0x7fffu + ((u >> 16) & 1u);   // RNE
    return (unsigned short)(r >> 16);
}
__device__ __forceinline__ float bf2f(unsigned short h) {
    return __uint_as_float(((unsigned)h) << 16);
}
__device__ __forceinline__ unsigned umin32(unsigned a, unsigned b) { return a < b ? a : b; }
__device__ __forceinline__ unsigned umax32(unsigned a, unsigned b) { return a > b ? a : b; }

__global__ __launch_bounds__(NTHREADS, 2) void vq_main(
    const float* __restrict__ x, const float* __restrict__ emb,
    int* __restrict__ counts2d, float* __restrict__ g_lossPart,
    float* __restrict__ out)
{
    __shared__ unsigned short ehs[KCODES * ESTR];   // 73728 B
    __shared__ unsigned short els[KCODES * ESTR];   // 73728 B
    __shared__ float esq_s[KCODES];                 // exact ||e||^2 (R1 order)
    __shared__ float e2b_s[KCODES];                 // ||e||^2 + BIAS
    __shared__ int   h_sh[KCODES];                  // block histogram
    __shared__ unsigned short idx_sh[8][32];
    __shared__ unsigned short flg_sh[8][32];
    __shared__ float wred[8];

    const int tid  = threadIdx.x;
    const int w    = tid >> 6;
    const int lane = tid & 63;
    const int m    = lane & 15;
    const int q    = lane >> 4;

    h_sh[tid] = 0;

    // ---- esq: thread t = code t, sequential fp32 order (matches R1 prep) ----
    {
        const float* e = emb + (size_t)tid * DIM;
        float s = 0.f;
        #pragma unroll
        for (int d4 = 0; d4 < DIM; d4 += 4) {
            f32x4 v = *(const f32x4*)&e[d4];
            s += v.x * v.x; s += v.y * v.y; s += v.z * v.z; s += v.w * v.w;
        }
        esq_s[tid] = s;
        e2b_s[tid] = s + BIAS;
    }

    // ---- stage + split codebook into LDS (once per block) ----
    #pragma unroll 4
    for (int i = 0; i < 16; ++i) {
        int f = tid + NTHREADS * i;                 // 0..8191
        int code = f >> 4, d4 = (f & 15) * 4;
        f32x4 v = *(const f32x4*)&emb[(size_t)code * DIM + d4];
        s16x4 hv, lv;
        #pragma unroll
        for (int j = 0; j < 4; ++j) {
            unsigned short h = f2bf(v[j]);
            hv[j] = (short)h;
            lv[j] = (short)f2bf(v[j] - bf2f(h));
        }
        *(s16x4*)&ehs[code * ESTR + d4] = hv;
        *(s16x4*)&els[code * ESTR + d4] = lv;
    }
    __syncthreads();

    // preload biased column norms for this lane's 32 (p,cg) columns
    float e2b_reg[32];
    #pragma unroll
    for (int p = 0; p < 4; ++p)
        #pragma unroll
        for (int cg = 0; cg < 8; ++cg)
            e2b_reg[p * 8 + cg] = e2b_s[p * 128 + cg * 16 + m];

    float lpart = 0.f;
    const int waveRow0 = blockIdx.x * 1024 + w * (TILES * 32);

    for (int t = 0; t < TILES; ++t) {
        const int T0 = waveRow0 + t * 32;

        // ---- x tile: global->reg (exact fp32 kept for epilogue) ----
        f32x4 xv[2][2][2];                          // [rg][kc][half]
        #pragma unroll
        for (int rg = 0; rg < 2; ++rg) {
            const float* px = &x[(size_t)(T0 + rg * 16 + m) * DIM + q * 8];
            xv[rg][0][0] = *(const f32x4*)&px[0];
            xv[rg][0][1] = *(const f32x4*)&px[4];
            xv[rg][1][0] = *(const f32x4*)&px[32];
            xv[rg][1][1] = *(const f32x4*)&px[36];
        }
        // ---- convert to bf16 hi/lo A-frags ----
        s16x8 axh[2][2], axl[2][2];
        #pragma unroll
        for (int rg = 0; rg < 2; ++rg)
            #pragma unroll
            for (int kc = 0; kc < 2; ++kc) {
                s16x8 h, l;
                #pragma unroll
                for (int hf = 0; hf < 2; ++hf)
                    #pragma unroll
                    for (int j = 0; j < 4; ++j) {
                        float v = xv[rg][kc][hf][j];
                        unsigned short hb = f2bf(v);
                        h[hf * 4 + j] = (short)hb;
                        l[hf * 4 + j] = (short)f2bf(v - bf2f(hb));
                    }
                axh[rg][kc] = h; axl[rg][kc] = l;
            }

        // ---- packed two-min state: uint = (bits(dist+BIAS) & ~31) | (p*8+cg) ----
        unsigned m1[2][4], m2[2][4];
        #pragma unroll
        for (int rg = 0; rg < 2; ++rg)
            #pragma unroll
            for (int r = 0; r < 4; ++r) { m1[rg][r] = 0xFFFFFFFFu; m2[rg][r] = 0xFFFFFFFFu; }

        for (int p = 0; p < 4; ++p) {
            f32x4 acc[2][8];
            #pragma unroll
            for (int rg = 0; rg < 2; ++rg)
                #pragma unroll
                for (int cg = 0; cg < 8; ++cg) acc[rg][cg] = (f32x4){0.f, 0.f, 0.f, 0.f};

            #pragma unroll
            for (int kc = 0; kc < 2; ++kc) {
                #pragma unroll
                for (int cg = 0; cg < 8; ++cg) {      // 8 independent 3-chains
                    const int off = (p * 128 + cg * 16 + m) * ESTR + kc * 32 + q * 8;
                    s16x8 bh = *(const s16x8*)&ehs[off];
                    s16x8 bl = *(const s16x8*)&els[off];
                    acc[0][cg] = __builtin_amdgcn_mfma_f32_16x16x32_bf16(axh[0][kc], bh, acc[0][cg], 0, 0, 0);
                    acc[0][cg] = __builtin_amdgcn_mfma_f32_16x16x32_bf16(axl[0][kc], bh, acc[0][cg], 0, 0, 0);
                    acc[0][cg] = __builtin_amdgcn_mfma_f32_16x16x32_bf16(axh[0][kc], bl, acc[0][cg], 0, 0, 0);
                    acc[1][cg] = __builtin_amdgcn_mfma_f32_16x16x32_bf16(axh[1][kc], bh, acc[1][cg], 0, 0, 0);
                    acc[1][cg] = __builtin_amdgcn_mfma_f32_16x16x32_bf16(axl[1][kc], bh, acc[1][cg], 0, 0, 0);
                    acc[1][cg] = __builtin_amdgcn_mfma_f32_16x16x32_bf16(axh[1][kc], bl, acc[1][cg], 0, 0, 0);
                }
            }
            // fold argmin: 5 VALU / element (fma, and_or, min, max, min)
            #pragma unroll
            for (int cg = 0; cg < 8; ++cg) {
                const unsigned pcg = (unsigned)(p * 8 + cg);
                const float e2b = e2b_reg[p * 8 + cg];
                #pragma unroll
                for (int rg = 0; rg < 2; ++rg)
                    #pragma unroll
                    for (int r = 0; r < 4; ++r) {
                        float db = fmaf(-2.f, acc[rg][cg][r], e2b);   // > 0 by BIAS
                        unsigned u = (__float_as_uint(db) & 0xFFFFFFE0u) | pcg;
                        unsigned a1 = m1[rg][r];
                        unsigned mx = umax32(a1, u);
                        m1[rg][r] = umin32(a1, u);
                        m2[rg][r] = umin32(m2[rg][r], mx);
                    }
            }
        }

        // ---- cross-lane (16 m-lanes) two-min combine ----
        unsigned om[2][4];
        #pragma unroll
        for (int rg = 0; rg < 2; ++rg)
            #pragma unroll
            for (int r = 0; r < 4; ++r) om[rg][r] = m1[rg][r];
        #pragma unroll
        for (int s = 1; s < 16; s <<= 1) {
            #pragma unroll
            for (int rg = 0; rg < 2; ++rg)
                #pragma unroll
                for (int r = 0; r < 4; ++r) {
                    unsigned o1 = (unsigned)__shfl_xor((int)m1[rg][r], s);
                    unsigned o2 = (unsigned)__shfl_xor((int)m2[rg][r], s);
                    unsigned mx = umax32(m1[rg][r], o1);
                    m1[rg][r] = umin32(m1[rg][r], o1);
                    m2[rg][r] = umin32(umin32(m2[rg][r], o2), mx);
                }
        }
        #pragma unroll
        for (int rg = 0; rg < 2; ++rg)
            #pragma unroll
            for (int r = 0; r < 4; ++r) {
                unsigned g1 = m1[rg][r], g2 = m2[rg][r];
                int rl = rg * 16 + q * 4 + r;
                if (om[rg][r] == g1) {                 // winner lane (ties -> flagged)
                    int pcg = (int)(g1 & 31u);
                    int col = (pcg >> 3) * 128 + (pcg & 7) * 16 + m;
                    idx_sh[w][rl] = (unsigned short)col;
                }
                if (m == 0) flg_sh[w][rl] = (unsigned short)((g2 - g1 < T5) ? 1 : 0);
            }

        // ---- exact fp32 resolve of flagged rows (rare; R1 formula/order) ----
        for (int row = 0; row < 32; ++row) {
            if (flg_sh[w][row]) {
                int grow = T0 + row;
                const float* xr = &x[(size_t)grow * DIM];
                float best = 3.4e38f; int bidx = 0;
                #pragma unroll
                for (int j = 0; j < 8; ++j) {
                    int c = lane * 8 + j;
                    const float* er = &emb[(size_t)c * DIM];
                    float dot = 0.f;
                    #pragma unroll
                    for (int d = 0; d < DIM; ++d) dot = fmaf(xr[d], er[d], dot);
                    float dist = esq_s[c] - 2.f * dot;
                    if (dist < best) { best = dist; bidx = c; }
                }
                #pragma unroll
                for (int s = 1; s < 64; s <<= 1) {
                    float ob = __shfl_xor(best, s);
                    int   oi = __shfl_xor(bidx, s);
                    if (ob < best || (ob == best && oi < bidx)) { best = ob; bidx = oi; }
                }
                if (lane == 0) idx_sh[w][row] = (unsigned short)bidx;
            }
        }

        // ---- histogram (LDS, low contention) ----
        if (lane < 32) atomicAdd(&h_sh[idx_sh[w][lane]], 1);

        // ---- epilogue: q_st + loss for ALL rows (round-1 op order) ----
        #pragma unroll
        for (int rg = 0; rg < 2; ++rg) {
            int rl = rg * 16 + m;
            int ki = idx_sh[w][rl];
            const float* er = &emb[(size_t)ki * DIM + q * 8];
            float* po = &out[(size_t)(T0 + rl) * DIM + q * 8];
            #pragma unroll
            for (int kc = 0; kc < 2; ++kc)
                #pragma unroll
                for (int hf = 0; hf < 2; ++hf) {
                    f32x4 ev = *(const f32x4*)&er[kc * 32 + hf * 4];
                    f32x4 xvv = xv[rg][kc][hf];
                    f32x4 fd, o;
                    #pragma unroll
                    for (int j = 0; j < 4; ++j) {
                        fd[j] = ev[j] - xvv[j];
                        o[j]  = xvv[j] + fd[j];
                        lpart += fd[j] * fd[j];
                    }
                    *(f32x4*)&po[kc * 32 + hf * 4] = o;
                }
        }
    }

    // ---- block outputs: histogram + loss partial (no global atomics) ----
    #pragma unroll
    for (int s = 32; s > 0; s >>= 1) lpart += __shfl_down(lpart, s);
    if (lane == 0) wred[w] = lpart;
    __syncthreads();
    counts2d[blockIdx.x * KCODES + tid] = h_sh[tid];
    if (tid == 0) {
        float s = 0.f;
        #pragma unroll
        for (int i = 0; i < 8; ++i) s += wred[i];
        g_lossPart[blockIdx.x] = s;
    }
}

__global__ __launch_bounds__(512) void vq_fin(const int* __restrict__ counts2d,
                                              const float* __restrict__ lossPart,
                                              float* __restrict__ out) {
    __shared__ float redp[8], redl[8];
    int k = threadIdx.x;
    int c = 0;
    for (int b = 0; b < NBLOCKS; ++b) c += counts2d[b * KCODES + k];
    float p = (float)c * (1.f / 262144.f);
    float t = p * logf(p + 1e-10f);
    float l = (k < 256) ? lossPart[k] : 0.f;
    #pragma unroll
    for (int off = 32; off > 0; off >>= 1) {
        t += __shfl_down(t, off);
        l += __shfl_down(l, off);
    }
    if ((k & 63) == 0) { redp[k >> 6] = t; redl[k >> 6] = l; }
    __syncthreads();
    if (k == 0) {
        float s = 0.f, ls = 0.f;
        #pragma unroll
        for (int i = 0; i < 8; ++i) { s += redp[i]; ls += redl[i]; }
        out[16777216] = ls * (0.25f / 16777216.f);
        out[16777217] = expf(-s);
    }
}

extern "C" void kernel_launch(void* const* d_in, const int* in_sizes, int n_in,
                              void* d_out, int out_size, void* d_ws, size_t ws_size,
                              hipStream_t stream) {
    const float* x   = (const float*)d_in[0];
    const float* emb = (const float*)d_in[1];
    float* out = (float*)d_out;

    char* ws = (char*)d_ws;
    int*   counts2d = (int*)(ws + 0);
    float* lossPart = (float*)(ws + 524288);

    vq_main<<<NBLOCKS, NTHREADS, 0, stream>>>(x, emb, counts2d, lossPart, out);
    vq_fin<<<1, 512, 0, stream>>>(counts2d, lossPart, out);
}